// Round 1
// baseline (1505.210 us; speedup 1.0000x reference)
//
#include <hip/hip_runtime.h>
#include <hip/hip_bf16.h>
#include <math.h>

// Problem constants (fixed by the reference)
#define NE   16      // experts
#define DDIM 1024    // embed dim
#define II   4096    // expert intermediate
#define ISD  2048    // shared intermediate
#define TT   4096    // tokens
#define CAP  512     // expert capacity

typedef __attribute__((ext_vector_type(8))) short short8;
typedef __attribute__((ext_vector_type(4))) float floatx4;

static __device__ __forceinline__ unsigned short f2b(float f){
  unsigned int x = __float_as_uint(f);
  return (unsigned short)((x + 0x7fffu + ((x >> 16) & 1u)) >> 16);  // RNE fp32->bf16
}

static __device__ __forceinline__ float gelu_exact(float x){
  return 0.5f * x * (1.0f + erff(x * 0.70710678118654752f));
}

// ---------------- gating: fp64 logits + softmax -> scores (E,T) fp32 ----------------
__global__ void gating_kernel(const float* __restrict__ x, const float* __restrict__ gw,
                              float* __restrict__ scores){
  const int wave = threadIdx.x >> 6, lane = threadIdx.x & 63;
  const int t = blockIdx.x * 4 + wave;
  const float* xp = x + (size_t)t * DDIM;
  float xr[16];
  #pragma unroll
  for (int i = 0; i < 16; i++) xr[i] = xp[i * 64 + lane];
  double logit[NE];
  #pragma unroll
  for (int e = 0; e < NE; e++){
    const float* g = gw + (size_t)e * DDIM;
    double s = 0.0;
    #pragma unroll
    for (int i = 0; i < 16; i++) s += (double)xr[i] * (double)g[i * 64 + lane];
    #pragma unroll
    for (int off = 32; off > 0; off >>= 1) s += __shfl_xor(s, off);
    logit[e] = s;
  }
  double m = logit[0];
  #pragma unroll
  for (int e = 1; e < NE; e++) m = fmax(m, logit[e]);
  double p[NE], sum = 0.0;
  #pragma unroll
  for (int e = 0; e < NE; e++){ p[e] = exp(logit[e] - m); sum += p[e]; }
  if (lane == 0){
    #pragma unroll
    for (int e = 0; e < NE; e++) scores[(size_t)e * TT + t] = (float)(p[e] / sum);
  }
}

// ---------------- top-k by rank counting (matches lax.top_k set semantics) ----------------
__global__ void topk_kernel(const float* __restrict__ scores, int* __restrict__ cnt,
                            int* __restrict__ tidx, float* __restrict__ tw){
  const int e = blockIdx.y;
  __shared__ float s[TT];
  const float* se = scores + (size_t)e * TT;
  for (int i = threadIdx.x; i < TT; i += 256) s[i] = se[i];
  __syncthreads();
  const int t = blockIdx.x * 256 + threadIdx.x;
  const float ms = s[t];
  int r = 0;
  const float4* s4 = reinterpret_cast<const float4*>(s);
  for (int j = 0; j < TT / 4; j++){
    float4 v = s4[j];
    int b = j * 4;
    r += (v.x > ms) || (v.x == ms && (b + 0) < t);
    r += (v.y > ms) || (v.y == ms && (b + 1) < t);
    r += (v.z > ms) || (v.z == ms && (b + 2) < t);
    r += (v.w > ms) || (v.w == ms && (b + 3) < t);
  }
  if (r < CAP){
    int p = atomicAdd(&cnt[e], 1);
    tidx[e * CAP + p] = t;
    tw[e * CAP + p]   = ms;
  }
}

// ---------------- gather selected token rows, fp32 -> bf16 ----------------
__global__ void gather_kernel(const float* __restrict__ x, const int* __restrict__ tidx,
                              unsigned short* __restrict__ Xg){
  const int ec = blockIdx.x;                 // 0 .. E*CAP-1
  const int tok = tidx[ec];
  const float4* src = reinterpret_cast<const float4*>(x + (size_t)tok * DDIM);
  ushort4* dst = reinterpret_cast<ushort4*>(Xg + (size_t)ec * DDIM);
  float4 v = src[threadIdx.x];
  ushort4 o; o.x = f2b(v.x); o.y = f2b(v.y); o.z = f2b(v.z); o.w = f2b(v.w);
  dst[threadIdx.x] = o;
}

// ---------------- fused gate+up GEMM: H = gelu(A Bg^T) * (A Bu^T), bf16 out ----------------
// A: MxK (TA = float or bf16 bits), Bg/Bu: NxK fp32 row-major. 128x128x32 tiles.
#define LDT 40
template<typename TA>
__launch_bounds__(256, 2)
__global__ void gateup_kernel(const TA* __restrict__ A, const float* __restrict__ Bg,
                              const float* __restrict__ Bu, unsigned short* __restrict__ H,
                              int M, int N, int K, long sA, long sB, long sH){
  __shared__ unsigned short As[128 * LDT];
  __shared__ unsigned short Bgs[128 * LDT];
  __shared__ unsigned short Bus[128 * LDT];
  const int tid = threadIdx.x;
  const int z = blockIdx.z;
  A  += (size_t)z * sA;  Bg += (size_t)z * sB;  Bu += (size_t)z * sB;  H += (size_t)z * sH;
  const int bm = blockIdx.x * 128, bn = blockIdx.y * 128;   // m varies fastest -> B-tile L2 reuse
  const int lane = tid & 63, wave = tid >> 6;
  const int wr = wave >> 1, wc = wave & 1;
  const int fr = lane & 15, fq = lane >> 4;

  floatx4 accG[4][4], accU[4][4];
  const floatx4 z4 = {0.f, 0.f, 0.f, 0.f};
  #pragma unroll
  for (int m = 0; m < 4; m++)
    #pragma unroll
    for (int n = 0; n < 4; n++){ accG[m][n] = z4; accU[m][n] = z4; }

  for (int k0 = 0; k0 < K; k0 += 32){
    #pragma unroll
    for (int p = 0; p < 4; p++){
      const int row = p * 32 + (tid >> 3);
      const int col = (tid & 7) * 4;
      if constexpr (__is_same(TA, float)){
        float4 v = *reinterpret_cast<const float4*>(A + (size_t)(bm + row) * K + k0 + col);
        ushort4 o; o.x = f2b(v.x); o.y = f2b(v.y); o.z = f2b(v.z); o.w = f2b(v.w);
        *reinterpret_cast<ushort4*>(&As[row * LDT + col]) = o;
      } else {
        *reinterpret_cast<ushort4*>(&As[row * LDT + col]) =
            *reinterpret_cast<const ushort4*>(A + (size_t)(bm + row) * K + k0 + col);
      }
      float4 vg = *reinterpret_cast<const float4*>(Bg + (size_t)(bn + row) * K + k0 + col);
      ushort4 og; og.x = f2b(vg.x); og.y = f2b(vg.y); og.z = f2b(vg.z); og.w = f2b(vg.w);
      *reinterpret_cast<ushort4*>(&Bgs[row * LDT + col]) = og;
      float4 vu = *reinterpret_cast<const float4*>(Bu + (size_t)(bn + row) * K + k0 + col);
      ushort4 ou; ou.x = f2b(vu.x); ou.y = f2b(vu.y); ou.z = f2b(vu.z); ou.w = f2b(vu.w);
      *reinterpret_cast<ushort4*>(&Bus[row * LDT + col]) = ou;
    }
    __syncthreads();
    short8 aF[4], gF[4], uF[4];
    #pragma unroll
    for (int m = 0; m < 4; m++)
      aF[m] = *reinterpret_cast<const short8*>(&As[(wr * 64 + m * 16 + fr) * LDT + fq * 8]);
    #pragma unroll
    for (int n = 0; n < 4; n++){
      gF[n] = *reinterpret_cast<const short8*>(&Bgs[(wc * 64 + n * 16 + fr) * LDT + fq * 8]);
      uF[n] = *reinterpret_cast<const short8*>(&Bus[(wc * 64 + n * 16 + fr) * LDT + fq * 8]);
    }
    #pragma unroll
    for (int m = 0; m < 4; m++)
      #pragma unroll
      for (int n = 0; n < 4; n++){
        accG[m][n] = __builtin_amdgcn_mfma_f32_16x16x32_bf16(aF[m], gF[n], accG[m][n], 0, 0, 0);
        accU[m][n] = __builtin_amdgcn_mfma_f32_16x16x32_bf16(aF[m], uF[n], accU[m][n], 0, 0, 0);
      }
    __syncthreads();
  }
  #pragma unroll
  for (int m = 0; m < 4; m++)
    #pragma unroll
    for (int n = 0; n < 4; n++){
      const int col  = bn + wc * 64 + n * 16 + fr;
      const int row0 = bm + wr * 64 + m * 16 + fq * 4;
      #pragma unroll
      for (int i = 0; i < 4; i++){
        float g = accG[m][n][i], u = accU[m][n][i];
        H[(size_t)(row0 + i) * N + col] = f2b(gelu_exact(g) * u);
      }
    }
}

// ---------------- down GEMM: C = A B^T. ATOMIC=1: scaled scatter-add, else plain store ----------------
template<int ATOMIC>
__launch_bounds__(256, 2)
__global__ void down_kernel(const unsigned short* __restrict__ A, const float* __restrict__ B,
                            float* __restrict__ out, const int* __restrict__ tidx,
                            const float* __restrict__ tw,
                            int M, int N, int K, long sA, long sB){
  __shared__ unsigned short As[128 * LDT];
  __shared__ unsigned short Bs[128 * LDT];
  const int tid = threadIdx.x;
  const int z = blockIdx.z;
  A += (size_t)z * sA;  B += (size_t)z * sB;
  const int bm = blockIdx.x * 128, bn = blockIdx.y * 128;
  const int lane = tid & 63, wave = tid >> 6;
  const int wr = wave >> 1, wc = wave & 1;
  const int fr = lane & 15, fq = lane >> 4;

  floatx4 acc[4][4];
  const floatx4 z4 = {0.f, 0.f, 0.f, 0.f};
  #pragma unroll
  for (int m = 0; m < 4; m++)
    #pragma unroll
    for (int n = 0; n < 4; n++) acc[m][n] = z4;

  for (int k0 = 0; k0 < K; k0 += 32){
    #pragma unroll
    for (int p = 0; p < 4; p++){
      const int row = p * 32 + (tid >> 3);
      const int col = (tid & 7) * 4;
      *reinterpret_cast<ushort4*>(&As[row * LDT + col]) =
          *reinterpret_cast<const ushort4*>(A + (size_t)(bm + row) * K + k0 + col);
      float4 v = *reinterpret_cast<const float4*>(B + (size_t)(bn + row) * K + k0 + col);
      ushort4 o; o.x = f2b(v.x); o.y = f2b(v.y); o.z = f2b(v.z); o.w = f2b(v.w);
      *reinterpret_cast<ushort4*>(&Bs[row * LDT + col]) = o;
    }
    __syncthreads();
    short8 aF[4], bF[4];
    #pragma unroll
    for (int m = 0; m < 4; m++)
      aF[m] = *reinterpret_cast<const short8*>(&As[(wr * 64 + m * 16 + fr) * LDT + fq * 8]);
    #pragma unroll
    for (int n = 0; n < 4; n++)
      bF[n] = *reinterpret_cast<const short8*>(&Bs[(wc * 64 + n * 16 + fr) * LDT + fq * 8]);
    #pragma unroll
    for (int m = 0; m < 4; m++)
      #pragma unroll
      for (int n = 0; n < 4; n++)
        acc[m][n] = __builtin_amdgcn_mfma_f32_16x16x32_bf16(aF[m], bF[n], acc[m][n], 0, 0, 0);
    __syncthreads();
  }
  #pragma unroll
  for (int m = 0; m < 4; m++)
    #pragma unroll
    for (int n = 0; n < 4; n++){
      const int col  = bn + wc * 64 + n * 16 + fr;
      const int row0 = bm + wr * 64 + m * 16 + fq * 4;
      #pragma unroll
      for (int i = 0; i < 4; i++){
        float val = acc[m][n][i];
        if constexpr (ATOMIC){
          const int r = row0 + i;
          const int token = tidx[z * CAP + r];
          const float wgt = tw[z * CAP + r];
          atomicAdd(&out[(size_t)token * DDIM + col], val * wgt);
        } else {
          out[(size_t)(row0 + i) * N + col] = val;
        }
      }
    }
}

extern "C" void kernel_launch(void* const* d_in, const int* in_sizes, int n_in,
                              void* d_out, int out_size, void* d_ws, size_t ws_size,
                              hipStream_t stream){
  const float* x  = (const float*)d_in[0];
  const float* gw = (const float*)d_in[1];
  const float* Wg = (const float*)d_in[2];
  const float* Wu = (const float*)d_in[3];
  const float* Wd = (const float*)d_in[4];
  const float* Sg = (const float*)d_in[5];
  const float* Su = (const float*)d_in[6];
  const float* Sd = (const float*)d_in[7];
  float* out = (float*)d_out;

  char* w = (char*)d_ws;
  float* scores        = (float*)w;           w += (size_t)NE * TT * 4;
  int*   cnt           = (int*)w;             w += 256;
  int*   tidx          = (int*)w;             w += (size_t)NE * CAP * 4;
  float* tw            = (float*)w;           w += (size_t)NE * CAP * 4;
  unsigned short* Xg   = (unsigned short*)w;  w += (size_t)NE * CAP * DDIM * 2;
  unsigned short* H    = (unsigned short*)w;  w += (size_t)NE * CAP * II * 2;
  unsigned short* Hs   = (unsigned short*)w;  w += (size_t)TT * ISD * 2;

  hipMemsetAsync(cnt, 0, NE * sizeof(int), stream);
  gating_kernel<<<TT / 4, 256, 0, stream>>>(x, gw, scores);
  topk_kernel<<<dim3(TT / 256, NE), 256, 0, stream>>>(scores, cnt, tidx, tw);
  gather_kernel<<<NE * CAP, 256, 0, stream>>>(x, tidx, Xg);

  // shared experts: Hs = gelu(x Sg^T) * (x Su^T); out = Hs Sd^T   (plain store, covers all of out)
  gateup_kernel<float><<<dim3(TT / 128, ISD / 128, 1), 256, 0, stream>>>(
      x, Sg, Su, Hs, TT, ISD, DDIM, 0, 0, 0);
  down_kernel<0><<<dim3(TT / 128, DDIM / 128, 1), 256, 0, stream>>>(
      Hs, Sd, out, nullptr, nullptr, TT, DDIM, ISD, 0, 0);

  // routed experts: H = gelu(Xg Wg^T) * (Xg Wu^T); out += w * (H Wd^T)  (atomic scatter-add)
  gateup_kernel<unsigned short><<<dim3(CAP / 128, II / 128, NE), 256, 0, stream>>>(
      Xg, Wg, Wu, H, CAP, II, DDIM, (long)CAP * DDIM, (long)II * DDIM, (long)CAP * II);
  down_kernel<1><<<dim3(CAP / 128, DDIM / 128, NE), 256, 0, stream>>>(
      H, Wd, out, tidx, tw, CAP, DDIM, II, (long)CAP * II, (long)DDIM * II);
}